// Round 10
// baseline (229.061 us; speedup 1.0000x reference)
//
#include <hip/hip_runtime.h>
#include <math.h>

#define BETA  0.125f    // 1/sqrt(64)
#define SHIFT 30.0f     // fixed softmax shift; logits bounded in [0.125, 68.5]
#define EPSF  1e-7f

typedef __attribute__((ext_vector_type(8))) short short8;
typedef __attribute__((ext_vector_type(4))) short short4v;
typedef __attribute__((ext_vector_type(4))) float f32x4;

__device__ __forceinline__ unsigned short bf16_rne(float x) {
  unsigned int u = __float_as_uint(x);
  return (unsigned short)((u + 0x7fffu + ((u >> 16) & 1u)) >> 16);
}
__device__ __forceinline__ float bf16_tof(unsigned short h) {
  return __uint_as_float(((unsigned int)h) << 16);
}
__device__ __forceinline__ void split2(float x, unsigned short& h, unsigned short& l) {
  unsigned int u = __float_as_uint(x);
  unsigned int hr = (u + 0x7fffu + ((u >> 16) & 1u)) & 0xffff0000u;  // RNE hi
  h = (unsigned short)(hr >> 16);
  l = bf16_rne(x - __uint_as_float(hr));
}
// split a float4 into hi/lo bf16 and store 8B to each LDS tile
__device__ __forceinline__ void store4(unsigned short* ph, unsigned short* pl, float4 v) {
  unsigned short h0, h1, h2, h3, l0, l1, l2, l3;
  split2(v.x, h0, l0); split2(v.y, h1, l1);
  split2(v.z, h2, l2); split2(v.w, h3, l3);
  *(uint2*)ph = make_uint2((unsigned)h0 | ((unsigned)h1 << 16),
                           (unsigned)h2 | ((unsigned)h3 << 16));
  *(uint2*)pl = make_uint2((unsigned)l0 | ((unsigned)l1 << 16),
                           (unsigned)l2 | ((unsigned)l3 << 16));
}

// Tacc (262144) + T0/L/WC (12288) floats, /4. STRICTLY within the proven
// footprint (R9 lesson: footprint end is exactly page-aligned; never exceed).
#define ZERO_F4 68608

// ---------------------------------------------------------------------------
// MFMA projection v2 (R7 champion — coalesced LDS staging). Per kc: stage
// X-slice + W-slice with coalesced float4 loads, split hi/lo bf16 once,
// [64][72]-u16 LDS tiles; MFMA frags from LDS b128. V stage-2 GEMM (K=64)
// reuses the overlaid region; Tr transpose overlays it too.
// Blocks 0..127: V; 128..255: K; 256..319: Q. Zeroes attention accumulators.
// ---------------------------------------------------------------------------
__global__ __launch_bounds__(256) void proj_kernel(
    const float* __restrict__ Xq, const float* __restrict__ Xk,
    const float* __restrict__ Xv,
    const float* __restrict__ Wq, const float* __restrict__ bq,
    const float* __restrict__ Wk, const float* __restrict__ bk,
    const float* __restrict__ Wv, const float* __restrict__ bv,
    float* __restrict__ Q0, float* __restrict__ K0, float* __restrict__ V0,
    unsigned short* __restrict__ Qh, unsigned short* __restrict__ Ql,
    unsigned short* __restrict__ Kh, unsigned short* __restrict__ Kl,
    unsigned short* __restrict__ Vh, unsigned short* __restrict__ Vl,
    unsigned short* __restrict__ Vth, unsigned short* __restrict__ Vtl,
    float* __restrict__ zeroRegion)
{
  __shared__ unsigned short LB[18432];

  const int bid = blockIdx.x;
  const int tid = threadIdx.x;

  {
    int idx = bid * 256 + tid;
    if (idx < ZERO_F4)
      *(float4*)&zeroRegion[idx * 4] = make_float4(0.f, 0.f, 0.f, 0.f);
  }

  const float *X, *W, *bias;
  float* y0;
  unsigned short *yh, *yl;
  bool dbl;
  int rowBase;
  if (bid < 128)      { X = Xv; W = Wk; bias = bk; y0 = V0; yh = Vh; yl = Vl; rowBase = bid << 6;         dbl = true;  }
  else if (bid < 256) { X = Xk; W = Wk; bias = bk; y0 = K0; yh = Kh; yl = Kl; rowBase = (bid - 128) << 6; dbl = false; }
  else                { X = Xq; W = Wq; bias = bq; y0 = Q0; yh = Qh; yl = Ql; rowBase = (bid - 256) << 6; dbl = false; }

  const int wave = tid >> 6, lane = tid & 63;
  const int lm = lane & 15;
  const int lg = lane >> 4;

  f32x4 acc[4];
#pragma unroll
  for (int nj = 0; nj < 4; ++nj) {
    float b = bias[nj * 16 + lm];
    acc[nj] = f32x4{b, b, b, b};
  }

  // ---- stage-1 GEMM: acc[nj] = X . W^T + bias (K=256, 4 kc rounds) ----
  for (int kc = 0; kc < 4; ++kc) {
#pragma unroll
    for (int q = 0; q < 4; ++q) {
      int f = tid + (q << 8);
      int r = f >> 4, g = f & 15;
      float4 xv = *(const float4*)&X[(rowBase + r) * 256 + (kc << 6) + (g << 2)];
      float4 wv = *(const float4*)&W[r * 256 + (kc << 6) + (g << 2)];
      int o = r * 72 + (g << 2);
      store4(&LB[o],         &LB[4608 + o],  xv);
      store4(&LB[9216 + o],  &LB[13824 + o], wv);
    }
    __syncthreads();
    short8 Ah2[2], Al2[2];
#pragma unroll
    for (int ks = 0; ks < 2; ++ks) {
      int ao = (wave * 16 + lm) * 72 + ks * 32 + lg * 8;
      Ah2[ks] = *(const short8*)&LB[ao];
      Al2[ks] = *(const short8*)&LB[4608 + ao];
    }
#pragma unroll
    for (int nj = 0; nj < 4; ++nj) {
#pragma unroll
      for (int ks = 0; ks < 2; ++ks) {
        int bo = (nj * 16 + lm) * 72 + ks * 32 + lg * 8;
        short8 Bh = *(const short8*)&LB[9216 + bo];
        short8 Bl = *(const short8*)&LB[13824 + bo];
        acc[nj] = __builtin_amdgcn_mfma_f32_16x16x32_bf16(Ah2[ks], Bh, acc[nj], 0, 0, 0);
        acc[nj] = __builtin_amdgcn_mfma_f32_16x16x32_bf16(Ah2[ks], Bl, acc[nj], 0, 0, 0);
        acc[nj] = __builtin_amdgcn_mfma_f32_16x16x32_bf16(Al2[ks], Bh, acc[nj], 0, 0, 0);
      }
    }
    __syncthreads();
  }

  // ---- stage-2 for V: Ve = Vk . Wv^T + bv (K=64), LDS-staged ----
  if (dbl) {
#pragma unroll
    for (int nj = 0; nj < 4; ++nj)
#pragma unroll
      for (int r = 0; r < 4; ++r) {
        unsigned short h, l;
        split2(acc[nj][r], h, l);
        int ro = (wave * 16 + lg * 4 + r) * 72 + nj * 16 + lm;
        LB[ro] = h;
        LB[4608 + ro] = l;
      }
#pragma unroll
    for (int q = 0; q < 4; ++q) {
      int f = tid + (q << 8);
      int r = f >> 4, g = f & 15;
      float4 wv = *(const float4*)&Wv[r * 64 + (g << 2)];
      int o = r * 72 + (g << 2);
      store4(&LB[9216 + o], &LB[13824 + o], wv);
    }
    __syncthreads();
    short8 A2h[2], A2l[2];
#pragma unroll
    for (int ks = 0; ks < 2; ++ks) {
      int ao = (wave * 16 + lm) * 72 + ks * 32 + lg * 8;
      A2h[ks] = *(const short8*)&LB[ao];
      A2l[ks] = *(const short8*)&LB[4608 + ao];
    }
#pragma unroll
    for (int nj = 0; nj < 4; ++nj) {
      float b = bv[nj * 16 + lm];
      acc[nj] = f32x4{b, b, b, b};
    }
#pragma unroll
    for (int nj = 0; nj < 4; ++nj) {
#pragma unroll
      for (int ks = 0; ks < 2; ++ks) {
        int bo = (nj * 16 + lm) * 72 + ks * 32 + lg * 8;
        short8 Bh = *(const short8*)&LB[9216 + bo];
        short8 Bl = *(const short8*)&LB[13824 + bo];
        acc[nj] = __builtin_amdgcn_mfma_f32_16x16x32_bf16(A2h[ks], Bh, acc[nj], 0, 0, 0);
        acc[nj] = __builtin_amdgcn_mfma_f32_16x16x32_bf16(A2h[ks], Bl, acc[nj], 0, 0, 0);
        acc[nj] = __builtin_amdgcn_mfma_f32_16x16x32_bf16(A2l[ks], Bh, acc[nj], 0, 0, 0);
      }
    }
  }

  // ---- expmap0 epilogue ----
  const int rowB = rowBase + (wave << 4);
  float n2p[4];
#pragma unroll
  for (int r = 0; r < 4; ++r)
    n2p[r] = acc[0][r] * acc[0][r] + acc[1][r] * acc[1][r] +
             acc[2][r] * acc[2][r] + acc[3][r] * acc[3][r];
#pragma unroll
  for (int r = 0; r < 4; ++r) {
    n2p[r] += __shfl_xor(n2p[r], 1);
    n2p[r] += __shfl_xor(n2p[r], 2);
    n2p[r] += __shfl_xor(n2p[r], 4);
    n2p[r] += __shfl_xor(n2p[r], 8);
  }
  unsigned short hv[4][4], lv[4][4];   // [r][nj]
#pragma unroll
  for (int r = 0; r < 4; ++r) {
    float n = sqrtf(n2p[r]);
    float factor = fminf(3.5f / (n + EPSF), 1.0f);
    float xn = fmaxf(n * factor, EPSF);
    float et = __expf(xn);
    float rt = __builtin_amdgcn_rcpf(et);
    float ch = 0.5f * (et + rt);
    float sh = 0.5f * (et - rt);
    float scale = sh * factor * __builtin_amdgcn_rcpf(xn);
    int row = rowB + lg * 4 + r;
    if (lm == 0) y0[row] = ch;
#pragma unroll
    for (int nj = 0; nj < 4; ++nj) {
      split2(acc[nj][r] * scale, hv[r][nj], lv[r][nj]);
      yh[row * 64 + nj * 16 + lm] = hv[r][nj];
      yl[row * 64 + nj * 16 + lm] = lv[r][nj];
    }
  }

  // ---- V transposed copies via Tr overlay (two passes: hi, lo) ----
  if (dbl) {
    __syncthreads();
    unsigned int* Tr = (unsigned int*)LB;   // [64][65]
#pragma unroll
    for (int r = 0; r < 4; ++r)
#pragma unroll
      for (int nj = 0; nj < 4; ++nj)
        Tr[(wave * 16 + lg * 4 + r) * 65 + nj * 16 + lm] = (unsigned int)hv[r][nj];
    __syncthreads();
#pragma unroll
    for (int q = 0; q < 2; ++q) {
      int f = tid + (q << 8);
      int d = f >> 3;
      int seg = (f & 7) << 3;
      unsigned int o[4];
#pragma unroll
      for (int k = 0; k < 4; ++k)
        o[k] = Tr[(seg + 2 * k) * 65 + d] | (Tr[(seg + 2 * k + 1) * 65 + d] << 16);
      *(uint4*)&Vth[d * 8192 + rowBase + seg] = make_uint4(o[0], o[1], o[2], o[3]);
    }
    __syncthreads();
#pragma unroll
    for (int r = 0; r < 4; ++r)
#pragma unroll
      for (int nj = 0; nj < 4; ++nj)
        Tr[(wave * 16 + lg * 4 + r) * 65 + nj * 16 + lm] = (unsigned int)lv[r][nj];
    __syncthreads();
#pragma unroll
    for (int q = 0; q < 2; ++q) {
      int f = tid + (q << 8);
      int d = f >> 3;
      int seg = (f & 7) << 3;
      unsigned int o[4];
#pragma unroll
      for (int k = 0; k < 4; ++k)
        o[k] = Tr[(seg + 2 * k) * 65 + d] | (Tr[(seg + 2 * k + 1) * 65 + d] << 16);
      *(uint4*)&Vtl[d * 8192 + rowBase + seg] = make_uint4(o[0], o[1], o[2], o[3]);
    }
  }
}

// ---------------------------------------------------------------------------
// MFMA attention core — R1/R7 champion main loop, UNCHANGED — plus OPTIONAL
// fused combine (active iff doneCnt != nullptr): the 16th slice-block per
// (b,sT) tile performs the combine for its 64 rows in-kernel. Coherence:
// device-scope atomics -> __threadfence -> counter; last block re-fences and
// reads accumulators via __hip_atomic_load(AGENT). No spinning; no
// dispatch-order assumption. doneCnt==nullptr -> classic 3-kernel path.
// ---------------------------------------------------------------------------
__global__ void __attribute__((amdgpu_waves_per_eu(4)))
__launch_bounds__(256) attn_kernel(
    const float* __restrict__ Q0g, const unsigned short* __restrict__ Qh,
    const unsigned short* __restrict__ Ql,
    const float* __restrict__ K0g, const unsigned short* __restrict__ Khg,
    const unsigned short* __restrict__ Klg,
    const float* __restrict__ V0g, const unsigned short* __restrict__ Vhg,
    const unsigned short* __restrict__ Vlg,
    const unsigned short* __restrict__ Vthg, const unsigned short* __restrict__ Vtlg,
    float* __restrict__ Tacc, float* __restrict__ T0acc,
    float* __restrict__ Lacc, float* __restrict__ WCacc,
    int* __restrict__ doneCnt, float* __restrict__ out)
{
  __shared__ unsigned short LB[16640];   // 33280 B
  __shared__ int lastFlag;

  const int tid = threadIdx.x;
  const int wave = tid >> 6, lane = tid & 63;
  const int lm = lane & 15;
  const int lg = lane >> 4;
  const int bid = blockIdx.x;          // 1024 blocks
  const int slice = bid & 15;          // SL = 16
  const int t = bid >> 4;              // 0..63 (= b*32 + sT)
  const int b = t >> 5;
  const int sT = t & 31;
  const int sBase = b * 2048 + sT * 64 + wave * 16;

  unsigned short* wbase = LB + 14336 + wave * 576;

  short8 qf[2][2];
#pragma unroll
  for (int ks = 0; ks < 2; ++ks) {
    int idx = (sBase + lm) * 64 + ks * 32 + lg * 8;
    qf[ks][0] = *(const short8*)(Qh + idx);
    qf[ks][1] = *(const short8*)(Ql + idx);
  }
  float q0r[4];
#pragma unroll
  for (int r = 0; r < 4; ++r) q0r[r] = Q0g[sBase + lg * 4 + r];

  f32x4 accT[4];
  float Lp[4], WCp[4], T0p[4];
#pragma unroll
  for (int r = 0; r < 4; ++r) { Lp[r] = 0.f; WCp[r] = 0.f; T0p[r] = 0.f; }
#pragma unroll
  for (int dj = 0; dj < 4; ++dj) accT[dj] = f32x4{0.f, 0.f, 0.f, 0.f};

  const int mSliceBase = b * 4096 + slice * 256;   // 8 chunks of 32
  const int srow = tid >> 3;
  const int sc8 = (tid & 7) << 3;
  const int drow = tid >> 2;
  const int dseg = (tid & 3) << 3;

  for (int mc = 0; mc < 8; ++mc) {
    const int mCh = mSliceBase + (mc << 5);

    {
      int goff = (mCh + srow) * 64 + sc8;
      int loff = srow * 72 + sc8;
      *(uint4*)&LB[loff]         = *(const uint4*)&Khg[goff];
      *(uint4*)&LB[2304 + loff]  = *(const uint4*)&Klg[goff];
      *(uint4*)&LB[4608 + loff]  = *(const uint4*)&Vhg[goff];
      *(uint4*)&LB[6912 + loff]  = *(const uint4*)&Vlg[goff];
      int gofft = drow * 8192 + mCh + dseg;
      int lofft = drow * 40 + dseg;
      *(uint4*)&LB[9216 + lofft]  = *(const uint4*)&Vthg[gofft];
      *(uint4*)&LB[11776 + lofft] = *(const uint4*)&Vtlg[gofft];
    }
    float k0r[2], v0r[2];
#pragma unroll
    for (int mj = 0; mj < 2; ++mj) {
      k0r[mj] = K0g[mCh + mj * 16 + lm];
      v0r[mj] = V0g[mCh + mj * 16 + lm];
    }
    __syncthreads();

#pragma unroll
    for (int mj = 0; mj < 2; ++mj) {
      f32x4 sims = f32x4{0.f, 0.f, 0.f, 0.f};
      f32x4 ipv  = f32x4{0.f, 0.f, 0.f, 0.f};
#pragma unroll
      for (int ks = 0; ks < 2; ++ks) {
        int off = (mj * 16 + lm) * 72 + ks * 32 + lg * 8;
        short8 kh = *(const short8*)&LB[off];
        short8 kl = *(const short8*)&LB[2304 + off];
        short8 vh = *(const short8*)&LB[4608 + off];
        short8 vl = *(const short8*)&LB[6912 + off];
        sims = __builtin_amdgcn_mfma_f32_16x16x32_bf16(qf[ks][0], kh, sims, 0, 0, 0);
        sims = __builtin_amdgcn_mfma_f32_16x16x32_bf16(qf[ks][0], kl, sims, 0, 0, 0);
        sims = __builtin_amdgcn_mfma_f32_16x16x32_bf16(qf[ks][1], kh, sims, 0, 0, 0);
        ipv  = __builtin_amdgcn_mfma_f32_16x16x32_bf16(qf[ks][0], vh, ipv, 0, 0, 0);
        ipv  = __builtin_amdgcn_mfma_f32_16x16x32_bf16(qf[ks][0], vl, ipv, 0, 0, 0);
        ipv  = __builtin_amdgcn_mfma_f32_16x16x32_bf16(qf[ks][1], vh, ipv, 0, 0, 0);
      }
#pragma unroll
      for (int r = 0; r < 4; ++r) {
        float c  = ipv[r]  - q0r[r] * v0r[mj];
        float sm = sims[r] - q0r[r] * k0r[mj];
        float x = -c;
        float s2 = fmaxf(fmaf(x, x, -1.0f), EPSF);
        float rs = __builtin_amdgcn_rsqf(s2);
        float dist = __logf(fmaf(s2, rs, x));
        float e = __expf(fmaf(-BETA, sm, -SHIFT));
        float w = e * dist * rs;
        unsigned short wu = bf16_rne(w);
        float wb = bf16_tof(wu);
        Lp[r]  += e;
        WCp[r] += wb * c;
        T0p[r] += wb * v0r[mj];
        wbase[(lg * 4 + r) * 36 + mj * 16 + lm] = wu;
      }
    }

    {
      short8 wa;
      {
        const unsigned short* p = wbase + lm * 36 + lg * 8;
        short4v a0 = *(const short4v*)p;
        short4v a1 = *(const short4v*)(p + 4);
        wa = __builtin_shufflevector(a0, a1, 0, 1, 2, 3, 4, 5, 6, 7);
      }
#pragma unroll
      for (int dj = 0; dj < 4; ++dj) {
        int off = (dj * 16 + lm) * 40 + lg * 8;
        short8 th = *(const short8*)&LB[9216 + off];
        short8 tl = *(const short8*)&LB[11776 + off];
        accT[dj] = __builtin_amdgcn_mfma_f32_16x16x32_bf16(wa, th, accT[dj], 0, 0, 0);
        accT[dj] = __builtin_amdgcn_mfma_f32_16x16x32_bf16(wa, tl, accT[dj], 0, 0, 0);
      }
    }
    __syncthreads();
  }

#pragma unroll
  for (int r = 0; r < 4; ++r)
#pragma unroll
    for (int off = 1; off < 16; off <<= 1) {
      Lp[r]  += __shfl_xor(Lp[r], off);
      WCp[r] += __shfl_xor(WCp[r], off);
      T0p[r] += __shfl_xor(T0p[r], off);
    }

#pragma unroll
  for (int r = 0; r < 4; ++r) {
    int row = sBase + lg * 4 + r;
#pragma unroll
    for (int dj = 0; dj < 4; ++dj)
      unsafeAtomicAdd(&Tacc[row * 64 + dj * 16 + lm], accT[dj][r]);
    if (lm == 0) {
      unsafeAtomicAdd(&Lacc[row],  Lp[r]);
      unsafeAtomicAdd(&WCacc[row], WCp[r]);
      unsafeAtomicAdd(&T0acc[row], T0p[r]);
    }
  }

  // ---- optional fused combine (workspace-gated from host) ----
  if (doneCnt == nullptr) return;

  __threadfence();
  if (tid == 0) lastFlag = atomicAdd(&doneCnt[t], 1);
  __syncthreads();
  if (lastFlag != 15) return;
  __threadfence();

  const int rowW = (t << 6) + (wave << 4);
  for (int rr = 0; rr < 16; ++rr) {
    int row = rowW + rr;
    int qi = row * 64 + lane;
    float Tsum = __hip_atomic_load(&Tacc[qi],   __ATOMIC_RELAXED, __HIP_MEMORY_SCOPE_AGENT);
    float T0   = __hip_atomic_load(&T0acc[row], __ATOMIC_RELAXED, __HIP_MEMORY_SCOPE_AGENT);
    float L    = __hip_atomic_load(&Lacc[row],  __ATOMIC_RELAXED, __HIP_MEMORY_SCOPE_AGENT);
    float WC   = __hip_atomic_load(&WCacc[row], __ATOMIC_RELAXED, __HIP_MEMORY_SCOPE_AGENT);

    float qd = bf16_tof(Qh[qi]) + bf16_tof(Ql[qi]);
    float q0 = Q0g[row];
    float invL = 1.0f / L;
    float td = Tsum * invL;
    float t0 = T0 * invL;
    float wc = WC * invL;

    double tt = (double)td * (double)td;
#pragma unroll
    for (int off = 1; off < 64; off <<= 1) tt += __shfl_xor(tt, off);
    tt -= (double)t0 * (double)t0;
    double mk = tt + (double)wc * (double)wc;

    float un = (float)sqrt(fmax(mk, 1e-12));
    float eu = __expf(un);
    float ru = 1.0f / eu;
    float ch = 0.5f * (eu + ru);
    float shu = 0.5f * (eu - ru) / un;

    float tmd = td + wc * qd;
    float tm0 = t0 + wc * q0;
    float zd = ch * qd + shu * tmd;
    float z0 = ch * q0 + shu * tm0;

    float p2 = zd * zd;
#pragma unroll
    for (int off = 1; off < 64; off <<= 1) p2 += __shfl_xor(p2, off);
    float yn = fmaxf(sqrtf(p2), EPSF);
    float zc = fmaxf(z0, 1.0f + EPSF);
    float dl = __logf(zc + sqrtf(fmaxf(zc * zc - 1.0f, 0.f)));
    out[qi] = dl * zd / yn;
  }
}

// ---------------------------------------------------------------------------
// Combine (fallback path — byte-identical to R7 champion).
// ---------------------------------------------------------------------------
__global__ __launch_bounds__(256) void combine_kernel(
    const float* __restrict__ Q0, const unsigned short* __restrict__ Qh,
    const unsigned short* __restrict__ Ql,
    const float* __restrict__ Tacc, const float* __restrict__ T0acc,
    const float* __restrict__ Lacc, const float* __restrict__ WCacc,
    float* __restrict__ out)
{
  int wid = (blockIdx.x << 2) + (threadIdx.x >> 6);
  int lane = threadIdx.x & 63;

  int qi = wid * 64 + lane;
  float Tsum = Tacc[qi];
  float T0 = T0acc[wid];
  float L  = Lacc[wid];
  float WC = WCacc[wid];

  float qd = bf16_tof(Qh[qi]) + bf16_tof(Ql[qi]);
  float q0 = Q0[wid];
  float invL = 1.0f / L;
  float td = Tsum * invL;
  float t0 = T0 * invL;
  float wc = WC * invL;

  double tt = (double)td * (double)td;
#pragma unroll
  for (int off = 1; off < 64; off <<= 1) tt += __shfl_xor(tt, off);
  tt -= (double)t0 * (double)t0;
  double mk = tt + (double)wc * (double)wc;

  float un = (float)sqrt(fmax(mk, 1e-12));
  float eu = __expf(un);
  float ru = 1.0f / eu;
  float ch = 0.5f * (eu + ru);
  float shu = 0.5f * (eu - ru) / un;

  float tmd = td + wc * qd;
  float tm0 = t0 + wc * q0;
  float zd = ch * qd + shu * tmd;
  float z0 = ch * q0 + shu * tm0;

  float p2 = zd * zd;
#pragma unroll
  for (int off = 1; off < 64; off <<= 1) p2 += __shfl_xor(p2, off);
  float yn = fmaxf(sqrtf(p2), EPSF);
  float zc = fmaxf(z0, 1.0f + EPSF);
  float dl = __logf(zc + sqrtf(fmaxf(zc * zc - 1.0f, 0.f)));
  out[qi] = dl * zd / yn;
}

// ---------------------------------------------------------------------------
extern "C" void kernel_launch(void* const* d_in, const int* in_sizes, int n_in,
                              void* d_out, int out_size, void* d_ws, size_t ws_size,
                              hipStream_t stream)
{
  const float* queries = (const float*)d_in[0];
  const float* keys    = (const float*)d_in[1];
  const float* values  = (const float*)d_in[2];
  const float* Wq      = (const float*)d_in[3];
  const float* bq      = (const float*)d_in[4];
  const float* Wk      = (const float*)d_in[5];
  const float* bk      = (const float*)d_in[6];
  const float* Wv      = (const float*)d_in[7];
  const float* bv      = (const float*)d_in[8];
  float* out = (float*)d_out;
  float* ws  = (float*)d_ws;

  float* Q0 = ws;                                   // 4096
  float* K0 = ws + 4096;                            // 8192
  float* V0 = ws + 12288;                           // 8192
  unsigned short* Qh  = (unsigned short*)(ws + 20480);
  unsigned short* Ql  = (unsigned short*)(ws + 151552);
  unsigned short* Kh  = (unsigned short*)(ws + 282624);
  unsigned short* Kl  = (unsigned short*)(ws + 544768);
  unsigned short* Vh  = (unsigned short*)(ws + 806912);
  unsigned short* Vl  = (unsigned short*)(ws + 1069056);
  unsigned short* Vth = (unsigned short*)(ws + 1331200);  // [64][8192]
  unsigned short* Vtl = (unsigned short*)(ws + 1593344);
  float* Tacc  = ws + 1855488;                      // 4096*64 = 262144
  float* T0acc = ws + 2117632;                      // 4096
  float* Lacc  = ws + 2121728;                      // 4096
  float* WCacc = ws + 2125824;                      // 4096
  // proven footprint ends at 2129920 floats (exactly page-aligned — R9 lesson)

  // fused-combine counters live past the proven footprint; only if ws allows
  const size_t baseFloats = 2129920;
  bool fused = ws_size >= baseFloats * sizeof(float) + 64 * sizeof(int);
  int* doneCnt = fused ? (int*)(ws + baseFloats) : nullptr;

  proj_kernel<<<320, 256, 0, stream>>>(queries, keys, values, Wq, bq, Wk, bk,
                                       Wv, bv, Q0, K0, V0, Qh, Ql, Kh, Kl,
                                       Vh, Vl, Vth, Vtl, Tacc);
  if (fused) {
    hipMemsetAsync(doneCnt, 0, 64 * sizeof(int), stream);
    attn_kernel<<<1024, 256, 0, stream>>>(
        Q0, Qh, Ql, K0, Kh, Kl, V0, Vh, Vl, Vth, Vtl,
        Tacc, T0acc, Lacc, WCacc, doneCnt, out);
  } else {
    attn_kernel<<<1024, 256, 0, stream>>>(
        Q0, Qh, Ql, K0, Kh, Kl, V0, Vh, Vl, Vth, Vtl,
        Tacc, T0acc, Lacc, WCacc, nullptr, nullptr);
    combine_kernel<<<1024, 256, 0, stream>>>(
        Q0, Qh, Ql, Tacc, T0acc, Lacc, WCacc, out);
  }
}

// Round 11
// 134.136 us; speedup vs baseline: 1.7077x; 1.7077x over previous
//
#include <hip/hip_runtime.h>
#include <math.h>

#define BETA  0.125f    // 1/sqrt(64)
#define SHIFT 30.0f     // fixed softmax shift; logits bounded in [0.125, 68.5]
#define EPSF  1e-7f

typedef __attribute__((ext_vector_type(8))) short short8;
typedef __attribute__((ext_vector_type(4))) short short4v;
typedef __attribute__((ext_vector_type(4))) float f32x4;

__device__ __forceinline__ unsigned short bf16_rne(float x) {
  unsigned int u = __float_as_uint(x);
  return (unsigned short)((u + 0x7fffu + ((u >> 16) & 1u)) >> 16);
}
__device__ __forceinline__ float bf16_tof(unsigned short h) {
  return __uint_as_float(((unsigned int)h) << 16);
}
__device__ __forceinline__ void split2(float x, unsigned short& h, unsigned short& l) {
  unsigned int u = __float_as_uint(x);
  unsigned int hr = (u + 0x7fffu + ((u >> 16) & 1u)) & 0xffff0000u;  // RNE hi
  h = (unsigned short)(hr >> 16);
  l = bf16_rne(x - __uint_as_float(hr));
}
// split a float4 into hi/lo bf16 and store 8B to each LDS tile
__device__ __forceinline__ void store4(unsigned short* ph, unsigned short* pl, float4 v) {
  unsigned short h0, h1, h2, h3, l0, l1, l2, l3;
  split2(v.x, h0, l0); split2(v.y, h1, l1);
  split2(v.z, h2, l2); split2(v.w, h3, l3);
  *(uint2*)ph = make_uint2((unsigned)h0 | ((unsigned)h1 << 16),
                           (unsigned)h2 | ((unsigned)h3 << 16));
  *(uint2*)pl = make_uint2((unsigned)l0 | ((unsigned)l1 << 16),
                           (unsigned)l2 | ((unsigned)l3 << 16));
}
// async global->LDS, 16B per lane; LDS dest = uniform base + lane*16 (HW)
__device__ __forceinline__ void gload_lds16(const unsigned short* g, unsigned short* l) {
  __builtin_amdgcn_global_load_lds(
      (const __attribute__((address_space(1))) unsigned int*)g,
      (__attribute__((address_space(3))) unsigned int*)l,
      16, 0, 0);
}

// Tacc (262144) + T0/L/WC (12288) floats, /4. Strictly within the proven
// footprint (R9 lesson: footprint end is page-aligned; never exceed).
#define ZERO_F4 68608

// ---------------------------------------------------------------------------
// MFMA projection v2 (R7 champion — coalesced LDS staging). Per kc: stage
// X-slice + W-slice with coalesced float4 loads, split hi/lo bf16 once,
// [64][72]-u16 LDS tiles; MFMA frags from LDS b128. V stage-2 GEMM (K=64)
// reuses the overlaid region; Tr transpose overlays it too.
// Blocks 0..127: V; 128..255: K; 256..319: Q. Zeroes attention accumulators.
// ---------------------------------------------------------------------------
__global__ __launch_bounds__(256) void proj_kernel(
    const float* __restrict__ Xq, const float* __restrict__ Xk,
    const float* __restrict__ Xv,
    const float* __restrict__ Wq, const float* __restrict__ bq,
    const float* __restrict__ Wk, const float* __restrict__ bk,
    const float* __restrict__ Wv, const float* __restrict__ bv,
    float* __restrict__ Q0, float* __restrict__ K0, float* __restrict__ V0,
    unsigned short* __restrict__ Qh, unsigned short* __restrict__ Ql,
    unsigned short* __restrict__ Kh, unsigned short* __restrict__ Kl,
    unsigned short* __restrict__ Vh, unsigned short* __restrict__ Vl,
    unsigned short* __restrict__ Vth, unsigned short* __restrict__ Vtl,
    float* __restrict__ zeroRegion)
{
  __shared__ unsigned short LB[18432];

  const int bid = blockIdx.x;
  const int tid = threadIdx.x;

  {
    int idx = bid * 256 + tid;
    if (idx < ZERO_F4)
      *(float4*)&zeroRegion[idx * 4] = make_float4(0.f, 0.f, 0.f, 0.f);
  }

  const float *X, *W, *bias;
  float* y0;
  unsigned short *yh, *yl;
  bool dbl;
  int rowBase;
  if (bid < 128)      { X = Xv; W = Wk; bias = bk; y0 = V0; yh = Vh; yl = Vl; rowBase = bid << 6;         dbl = true;  }
  else if (bid < 256) { X = Xk; W = Wk; bias = bk; y0 = K0; yh = Kh; yl = Kl; rowBase = (bid - 128) << 6; dbl = false; }
  else                { X = Xq; W = Wq; bias = bq; y0 = Q0; yh = Qh; yl = Ql; rowBase = (bid - 256) << 6; dbl = false; }

  const int wave = tid >> 6, lane = tid & 63;
  const int lm = lane & 15;
  const int lg = lane >> 4;

  f32x4 acc[4];
#pragma unroll
  for (int nj = 0; nj < 4; ++nj) {
    float b = bias[nj * 16 + lm];
    acc[nj] = f32x4{b, b, b, b};
  }

  // ---- stage-1 GEMM: acc[nj] = X . W^T + bias (K=256, 4 kc rounds) ----
  for (int kc = 0; kc < 4; ++kc) {
#pragma unroll
    for (int q = 0; q < 4; ++q) {
      int f = tid + (q << 8);
      int r = f >> 4, g = f & 15;
      float4 xv = *(const float4*)&X[(rowBase + r) * 256 + (kc << 6) + (g << 2)];
      float4 wv = *(const float4*)&W[r * 256 + (kc << 6) + (g << 2)];
      int o = r * 72 + (g << 2);
      store4(&LB[o],         &LB[4608 + o],  xv);
      store4(&LB[9216 + o],  &LB[13824 + o], wv);
    }
    __syncthreads();
    short8 Ah2[2], Al2[2];
#pragma unroll
    for (int ks = 0; ks < 2; ++ks) {
      int ao = (wave * 16 + lm) * 72 + ks * 32 + lg * 8;
      Ah2[ks] = *(const short8*)&LB[ao];
      Al2[ks] = *(const short8*)&LB[4608 + ao];
    }
#pragma unroll
    for (int nj = 0; nj < 4; ++nj) {
#pragma unroll
      for (int ks = 0; ks < 2; ++ks) {
        int bo = (nj * 16 + lm) * 72 + ks * 32 + lg * 8;
        short8 Bh = *(const short8*)&LB[9216 + bo];
        short8 Bl = *(const short8*)&LB[13824 + bo];
        acc[nj] = __builtin_amdgcn_mfma_f32_16x16x32_bf16(Ah2[ks], Bh, acc[nj], 0, 0, 0);
        acc[nj] = __builtin_amdgcn_mfma_f32_16x16x32_bf16(Ah2[ks], Bl, acc[nj], 0, 0, 0);
        acc[nj] = __builtin_amdgcn_mfma_f32_16x16x32_bf16(Al2[ks], Bh, acc[nj], 0, 0, 0);
      }
    }
    __syncthreads();
  }

  // ---- stage-2 for V: Ve = Vk . Wv^T + bv (K=64), LDS-staged ----
  if (dbl) {
#pragma unroll
    for (int nj = 0; nj < 4; ++nj)
#pragma unroll
      for (int r = 0; r < 4; ++r) {
        unsigned short h, l;
        split2(acc[nj][r], h, l);
        int ro = (wave * 16 + lg * 4 + r) * 72 + nj * 16 + lm;
        LB[ro] = h;
        LB[4608 + ro] = l;
      }
#pragma unroll
    for (int q = 0; q < 4; ++q) {
      int f = tid + (q << 8);
      int r = f >> 4, g = f & 15;
      float4 wv = *(const float4*)&Wv[r * 64 + (g << 2)];
      int o = r * 72 + (g << 2);
      store4(&LB[9216 + o], &LB[13824 + o], wv);
    }
    __syncthreads();
    short8 A2h[2], A2l[2];
#pragma unroll
    for (int ks = 0; ks < 2; ++ks) {
      int ao = (wave * 16 + lm) * 72 + ks * 32 + lg * 8;
      A2h[ks] = *(const short8*)&LB[ao];
      A2l[ks] = *(const short8*)&LB[4608 + ao];
    }
#pragma unroll
    for (int nj = 0; nj < 4; ++nj) {
      float b = bv[nj * 16 + lm];
      acc[nj] = f32x4{b, b, b, b};
    }
#pragma unroll
    for (int nj = 0; nj < 4; ++nj) {
#pragma unroll
      for (int ks = 0; ks < 2; ++ks) {
        int bo = (nj * 16 + lm) * 72 + ks * 32 + lg * 8;
        short8 Bh = *(const short8*)&LB[9216 + bo];
        short8 Bl = *(const short8*)&LB[13824 + bo];
        acc[nj] = __builtin_amdgcn_mfma_f32_16x16x32_bf16(A2h[ks], Bh, acc[nj], 0, 0, 0);
        acc[nj] = __builtin_amdgcn_mfma_f32_16x16x32_bf16(A2h[ks], Bl, acc[nj], 0, 0, 0);
        acc[nj] = __builtin_amdgcn_mfma_f32_16x16x32_bf16(A2l[ks], Bh, acc[nj], 0, 0, 0);
      }
    }
  }

  // ---- expmap0 epilogue ----
  const int rowB = rowBase + (wave << 4);
  float n2p[4];
#pragma unroll
  for (int r = 0; r < 4; ++r)
    n2p[r] = acc[0][r] * acc[0][r] + acc[1][r] * acc[1][r] +
             acc[2][r] * acc[2][r] + acc[3][r] * acc[3][r];
#pragma unroll
  for (int r = 0; r < 4; ++r) {
    n2p[r] += __shfl_xor(n2p[r], 1);
    n2p[r] += __shfl_xor(n2p[r], 2);
    n2p[r] += __shfl_xor(n2p[r], 4);
    n2p[r] += __shfl_xor(n2p[r], 8);
  }
  unsigned short hv[4][4], lv[4][4];   // [r][nj]
#pragma unroll
  for (int r = 0; r < 4; ++r) {
    float n = sqrtf(n2p[r]);
    float factor = fminf(3.5f / (n + EPSF), 1.0f);
    float xn = fmaxf(n * factor, EPSF);
    float et = __expf(xn);
    float rt = __builtin_amdgcn_rcpf(et);
    float ch = 0.5f * (et + rt);
    float sh = 0.5f * (et - rt);
    float scale = sh * factor * __builtin_amdgcn_rcpf(xn);
    int row = rowB + lg * 4 + r;
    if (lm == 0) y0[row] = ch;
#pragma unroll
    for (int nj = 0; nj < 4; ++nj) {
      split2(acc[nj][r] * scale, hv[r][nj], lv[r][nj]);
      yh[row * 64 + nj * 16 + lm] = hv[r][nj];
      yl[row * 64 + nj * 16 + lm] = lv[r][nj];
    }
  }

  // ---- V transposed copies via Tr overlay (two passes: hi, lo) ----
  if (dbl) {
    __syncthreads();
    unsigned int* Tr = (unsigned int*)LB;   // [64][65]
#pragma unroll
    for (int r = 0; r < 4; ++r)
#pragma unroll
      for (int nj = 0; nj < 4; ++nj)
        Tr[(wave * 16 + lg * 4 + r) * 65 + nj * 16 + lm] = (unsigned int)hv[r][nj];
    __syncthreads();
#pragma unroll
    for (int q = 0; q < 2; ++q) {
      int f = tid + (q << 8);
      int d = f >> 3;
      int seg = (f & 7) << 3;
      unsigned int o[4];
#pragma unroll
      for (int k = 0; k < 4; ++k)
        o[k] = Tr[(seg + 2 * k) * 65 + d] | (Tr[(seg + 2 * k + 1) * 65 + d] << 16);
      *(uint4*)&Vth[d * 8192 + rowBase + seg] = make_uint4(o[0], o[1], o[2], o[3]);
    }
    __syncthreads();
#pragma unroll
    for (int r = 0; r < 4; ++r)
#pragma unroll
      for (int nj = 0; nj < 4; ++nj)
        Tr[(wave * 16 + lg * 4 + r) * 65 + nj * 16 + lm] = (unsigned int)lv[r][nj];
    __syncthreads();
#pragma unroll
    for (int q = 0; q < 2; ++q) {
      int f = tid + (q << 8);
      int d = f >> 3;
      int seg = (f & 7) << 3;
      unsigned int o[4];
#pragma unroll
      for (int k = 0; k < 4; ++k)
        o[k] = Tr[(seg + 2 * k) * 65 + d] | (Tr[(seg + 2 * k + 1) * 65 + d] << 16);
      *(uint4*)&Vtl[d * 8192 + rowBase + seg] = make_uint4(o[0], o[1], o[2], o[3]);
    }
  }
}

// ---------------------------------------------------------------------------
// MFMA attention core — R7 champion main loop, with ONE change: the 4 K/V
// staging tiles use width-16 __builtin_amdgcn_global_load_lds into LINEAR
// unpadded [32][64]-u16 tiles (each wave owns 8 rows = 64 lanes x 16B, no
// VGPR round-trip). Unpadded 128B rows would 16-way-conflict Phase A reads
// (G4), so the T2 involution is applied BOTH sides (#21): global source
// chunk pre-swizzled c^(row&7); Phase-A read chunk (ks*4+lg)^(lm&7) ->
// 8 lanes per bank-quad (minimum). Vt/W tiles and all math unchanged.
// LDS 33280 -> 31232 B. R10 lesson: no device-scope fences on block exit.
// ---------------------------------------------------------------------------
__global__ void __attribute__((amdgpu_waves_per_eu(4)))
__launch_bounds__(256) attn_kernel(
    const float* __restrict__ Q0g, const unsigned short* __restrict__ Qh,
    const unsigned short* __restrict__ Ql,
    const float* __restrict__ K0g, const unsigned short* __restrict__ Khg,
    const unsigned short* __restrict__ Klg,
    const float* __restrict__ V0g, const unsigned short* __restrict__ Vhg,
    const unsigned short* __restrict__ Vlg,
    const unsigned short* __restrict__ Vthg, const unsigned short* __restrict__ Vtlg,
    float* __restrict__ Tacc, float* __restrict__ T0acc,
    float* __restrict__ Lacc, float* __restrict__ WCacc)
{
  // LDS layout (u16 units):
  //   Kh@0  Kl@2048  Vh@4096  Vl@6144   (each 32x64 linear, chunk-swizzled)
  //   Vth@8192  Vtl@10752               (each 64 rows x 40, 16B-aligned rows)
  //   W@13312 + wave*576                (per-wave 16 x 36, dedicated)
  __shared__ unsigned short LB[15616];   // 31232 B

  const int tid = threadIdx.x;
  const int wave = tid >> 6, lane = tid & 63;
  const int lm = lane & 15;
  const int lg = lane >> 4;
  const int bid = blockIdx.x;          // 1024 blocks
  const int slice = bid & 15;          // SL = 16
  const int t = bid >> 4;              // 0..63
  const int b = t >> 5;
  const int sT = t & 31;
  const int sBase = b * 2048 + sT * 64 + wave * 16;

  unsigned short* wbase = LB + 13312 + wave * 576;

  // loop-invariant Q fragments [kstep][hi/lo]
  short8 qf[2][2];
#pragma unroll
  for (int ks = 0; ks < 2; ++ks) {
    int idx = (sBase + lm) * 64 + ks * 32 + lg * 8;
    qf[ks][0] = *(const short8*)(Qh + idx);
    qf[ks][1] = *(const short8*)(Ql + idx);
  }
  float q0r[4];
#pragma unroll
  for (int r = 0; r < 4; ++r) q0r[r] = Q0g[sBase + lg * 4 + r];

  f32x4 accT[4];
  float Lp[4], WCp[4], T0p[4];
#pragma unroll
  for (int r = 0; r < 4; ++r) { Lp[r] = 0.f; WCp[r] = 0.f; T0p[r] = 0.f; }
#pragma unroll
  for (int dj = 0; dj < 4; ++dj) accT[dj] = f32x4{0.f, 0.f, 0.f, 0.f};

  const int mSliceBase = b * 4096 + slice * 256;   // 8 chunks of 32
  // K/V staging (global_load_lds): wave owns rows [wave*8, wave*8+8) of the
  // 32-row chunk; lane l -> row wave*8+(l>>3), LDS chunk l&7 (linear), global
  // chunk (l&7)^(l>>3) (involution with read-side swizzle).
  const int rl   = (wave << 3) + (lane >> 3);          // tile-local row
  const int csrc = (((lane & 7) ^ (lane >> 3)) << 3);  // swizzled src (u16)
  unsigned short* kvdst = LB + (wave << 9);            // wave*512 u16
  const int drow = tid >> 2;            // 0..63 (Vt tile row = d)
  const int dseg = (tid & 3) << 3;      // 0,8,16,24

  for (int mc = 0; mc < 8; ++mc) {
    const int mCh = mSliceBase + (mc << 5);

    // ---- stage: 4 K/V tiles via global_load_lds + 2 Vt tiles via regs ----
    {
      int goff = (mCh + rl) * 64 + csrc;
      gload_lds16(Khg + goff, kvdst);
      gload_lds16(Klg + goff, kvdst + 2048);
      gload_lds16(Vhg + goff, kvdst + 4096);
      gload_lds16(Vlg + goff, kvdst + 6144);
      int gofft = drow * 8192 + mCh + dseg;        // Vt global: [d][8192]
      int lofft = drow * 40 + dseg;
      *(uint4*)&LB[8192 + lofft]  = *(const uint4*)&Vthg[gofft];
      *(uint4*)&LB[10752 + lofft] = *(const uint4*)&Vtlg[gofft];
    }
    float k0r[2], v0r[2];
#pragma unroll
    for (int mj = 0; mj < 2; ++mj) {
      k0r[mj] = K0g[mCh + mj * 16 + lm];
      v0r[mj] = V0g[mCh + mj * 16 + lm];
    }
    __syncthreads();   // drains vmcnt (incl. global_load_lds) before reads

    // ---- per m-block: sims/ipv MFMAs + elementwise + W write ----
#pragma unroll
    for (int mj = 0; mj < 2; ++mj) {
      f32x4 sims = f32x4{0.f, 0.f, 0.f, 0.f};
      f32x4 ipv  = f32x4{0.f, 0.f, 0.f, 0.f};
#pragma unroll
      for (int ks = 0; ks < 2; ++ks) {
        int row = mj * 16 + lm;
        int off = (row << 6) + (((((ks << 2) + lg)) ^ (lm & 7)) << 3);
        short8 kh = *(const short8*)&LB[off];
        short8 kl = *(const short8*)&LB[2048 + off];
        short8 vh = *(const short8*)&LB[4096 + off];
        short8 vl = *(const short8*)&LB[6144 + off];
        sims = __builtin_amdgcn_mfma_f32_16x16x32_bf16(qf[ks][0], kh, sims, 0, 0, 0);
        sims = __builtin_amdgcn_mfma_f32_16x16x32_bf16(qf[ks][0], kl, sims, 0, 0, 0);
        sims = __builtin_amdgcn_mfma_f32_16x16x32_bf16(qf[ks][1], kh, sims, 0, 0, 0);
        ipv  = __builtin_amdgcn_mfma_f32_16x16x32_bf16(qf[ks][0], vh, ipv, 0, 0, 0);
        ipv  = __builtin_amdgcn_mfma_f32_16x16x32_bf16(qf[ks][0], vl, ipv, 0, 0, 0);
        ipv  = __builtin_amdgcn_mfma_f32_16x16x32_bf16(qf[ks][1], vh, ipv, 0, 0, 0);
      }
      // w = e * acosh(-c) * rsq(c^2-1)
#pragma unroll
      for (int r = 0; r < 4; ++r) {
        float c  = ipv[r]  - q0r[r] * v0r[mj];
        float sm = sims[r] - q0r[r] * k0r[mj];
        float x = -c;
        float s2 = fmaxf(fmaf(x, x, -1.0f), EPSF);
        float rs = __builtin_amdgcn_rsqf(s2);
        float dist = __logf(fmaf(s2, rs, x));
        float e = __expf(fmaf(-BETA, sm, -SHIFT));
        float w = e * dist * rs;
        unsigned short wu = bf16_rne(w);
        float wb = bf16_tof(wu);
        Lp[r]  += e;
        WCp[r] += wb * c;
        T0p[r] += wb * v0r[mj];
        wbase[(lg * 4 + r) * 36 + mj * 16 + lm] = wu;
      }
    }

    // ---- Phase B: T[s][d] += W[s][m] * V[m][d]  (A=own-wave W, B=Vt) ----
    {
      short8 wa;
      {
        const unsigned short* p = wbase + lm * 36 + lg * 8;
        short4v a0 = *(const short4v*)p;
        short4v a1 = *(const short4v*)(p + 4);
        wa = __builtin_shufflevector(a0, a1, 0, 1, 2, 3, 4, 5, 6, 7);
      }
#pragma unroll
      for (int dj = 0; dj < 4; ++dj) {
        int off = (dj * 16 + lm) * 40 + lg * 8;
        short8 th = *(const short8*)&LB[8192 + off];
        short8 tl = *(const short8*)&LB[10752 + off];
        accT[dj] = __builtin_amdgcn_mfma_f32_16x16x32_bf16(wa, th, accT[dj], 0, 0, 0);
        accT[dj] = __builtin_amdgcn_mfma_f32_16x16x32_bf16(wa, tl, accT[dj], 0, 0, 0);
      }
    }
    __syncthreads();  // tiles consumed before next chunk's staging
  }

  // reduce row scalars across the 16 col-lanes
#pragma unroll
  for (int r = 0; r < 4; ++r)
#pragma unroll
    for (int off = 1; off < 16; off <<= 1) {
      Lp[r]  += __shfl_xor(Lp[r], off);
      WCp[r] += __shfl_xor(WCp[r], off);
      T0p[r] += __shfl_xor(T0p[r], off);
    }

  // atomic accumulation across slices (HW f32 atomics; fire-and-forget,
  // NO fence on exit path — R10 lesson)
#pragma unroll
  for (int r = 0; r < 4; ++r) {
    int row = sBase + lg * 4 + r;
#pragma unroll
    for (int dj = 0; dj < 4; ++dj)
      unsafeAtomicAdd(&Tacc[row * 64 + dj * 16 + lm], accT[dj][r]);
    if (lm == 0) {
      unsafeAtomicAdd(&Lacc[row],  Lp[r]);
      unsafeAtomicAdd(&WCacc[row], WCp[r]);
      unsafeAtomicAdd(&T0acc[row], T0p[r]);
    }
  }
}

// ---------------------------------------------------------------------------
// Combine (r9-proven champion): one wave per (b,s) row. f32 fast math; f64
// only for the <t,t> reduction feeding the tangency identity mk = <t,t>+wc^2.
// ---------------------------------------------------------------------------
__global__ __launch_bounds__(256) void combine_kernel(
    const float* __restrict__ Q0, const unsigned short* __restrict__ Qh,
    const unsigned short* __restrict__ Ql,
    const float* __restrict__ Tacc, const float* __restrict__ T0acc,
    const float* __restrict__ Lacc, const float* __restrict__ WCacc,
    float* __restrict__ out)
{
  int wid = (blockIdx.x << 2) + (threadIdx.x >> 6);
  int lane = threadIdx.x & 63;

  int qi = wid * 64 + lane;
  float Tsum = Tacc[qi];
  float T0 = T0acc[wid];
  float L  = Lacc[wid];
  float WC = WCacc[wid];

  float qd = bf16_tof(Qh[qi]) + bf16_tof(Ql[qi]);
  float q0 = Q0[wid];
  float invL = 1.0f / L;
  float td = Tsum * invL;
  float t0 = T0 * invL;
  float wc = WC * invL;

  double tt = (double)td * (double)td;
#pragma unroll
  for (int off = 1; off < 64; off <<= 1) tt += __shfl_xor(tt, off);
  tt -= (double)t0 * (double)t0;
  double mk = tt + (double)wc * (double)wc;

  float un = (float)sqrt(fmax(mk, 1e-12));
  float eu = __expf(un);
  float ru = 1.0f / eu;
  float ch = 0.5f * (eu + ru);
  float shu = 0.5f * (eu - ru) / un;

  float tmd = td + wc * qd;
  float tm0 = t0 + wc * q0;
  float zd = ch * qd + shu * tmd;
  float z0 = ch * q0 + shu * tm0;

  float p2 = zd * zd;
#pragma unroll
  for (int off = 1; off < 64; off <<= 1) p2 += __shfl_xor(p2, off);
  float yn = fmaxf(sqrtf(p2), EPSF);
  float zc = fmaxf(z0, 1.0f + EPSF);
  float dl = __logf(zc + sqrtf(fmaxf(zc * zc - 1.0f, 0.f)));
  out[qi] = dl * zd / yn;
}

// ---------------------------------------------------------------------------
extern "C" void kernel_launch(void* const* d_in, const int* in_sizes, int n_in,
                              void* d_out, int out_size, void* d_ws, size_t ws_size,
                              hipStream_t stream)
{
  const float* queries = (const float*)d_in[0];
  const float* keys    = (const float*)d_in[1];
  const float* values  = (const float*)d_in[2];
  const float* Wq      = (const float*)d_in[3];
  const float* bq      = (const float*)d_in[4];
  const float* Wk      = (const float*)d_in[5];
  const float* bk      = (const float*)d_in[6];
  const float* Wv      = (const float*)d_in[7];
  const float* bv      = (const float*)d_in[8];
  float* out = (float*)d_out;
  float* ws  = (float*)d_ws;

  float* Q0 = ws;                                   // 4096
  float* K0 = ws + 4096;                            // 8192
  float* V0 = ws + 12288;                           // 8192
  unsigned short* Qh  = (unsigned short*)(ws + 20480);
  unsigned short* Ql  = (unsigned short*)(ws + 151552);
  unsigned short* Kh  = (unsigned short*)(ws + 282624);
  unsigned short* Kl  = (unsigned short*)(ws + 544768);
  unsigned short* Vh  = (unsigned short*)(ws + 806912);
  unsigned short* Vl  = (unsigned short*)(ws + 1069056);
  unsigned short* Vth = (unsigned short*)(ws + 1331200);  // [64][8192]
  unsigned short* Vtl = (unsigned short*)(ws + 1593344);
  float* Tacc  = ws + 1855488;                      // 4096*64 = 262144
  float* T0acc = ws + 2117632;                      // 4096
  float* Lacc  = ws + 2121728;                      // 4096
  float* WCacc = ws + 2125824;                      // 4096

  proj_kernel<<<320, 256, 0, stream>>>(queries, keys, values, Wq, bq, Wk, bk,
                                       Wv, bv, Q0, K0, V0, Qh, Ql, Kh, Kl,
                                       Vh, Vl, Vth, Vtl, Tacc);
  attn_kernel<<<1024, 256, 0, stream>>>(
      Q0, Qh, Ql, K0, Kh, Kl, V0, Vh, Vl, Vth, Vtl,
      Tacc, T0acc, Lacc, WCacc);
  combine_kernel<<<1024, 256, 0, stream>>>(
      Q0, Qh, Ql, Tacc, T0acc, Lacc, WCacc, out);
}